// Round 9
// baseline (379.035 us; speedup 1.0000x reference)
//
#include <hip/hip_runtime.h>
#include <math.h>

// Problem constants (from reference)
#define NN 50000
#define EE 800000
#define NBK 196    // node buckets (256 nodes each): ceil(50000/256)
#define EPB 4096   // edges per pass-A block: ceil(800000/4096) = 196 blocks

typedef short v8s __attribute__((ext_vector_type(8)));
typedef float v4f __attribute__((ext_vector_type(4)));

__device__ __forceinline__ ushort f2bf(float f) {
    uint u = __float_as_uint(f);
    uint r = (u + 0x7fffu + ((u >> 16) & 1u)) >> 16;
    return (ushort)r;
}
__device__ __forceinline__ float bf2f(ushort h) {
    return __uint_as_float(((uint)h) << 16);
}

// async global->LDS, 16B per lane (dest = wave-uniform base + lane*16)
__device__ __forceinline__ void gld_lds16(const void* g, void* l) {
    __builtin_amdgcn_global_load_lds(
        (const __attribute__((address_space(1))) void*)g,
        (__attribute__((address_space(3))) void*)l, 16, 0, 0);
}

// DPP partial reductions (no LDS pipe).
template <int CTRL>
__device__ __forceinline__ float dppadd(float x) {
    int y = __builtin_amdgcn_update_dpp(0, __float_as_int(x), CTRL, 0xf, 0xf, true);
    return x + __int_as_float(y);
}
__device__ __forceinline__ float sum8(float x) {   // sum within aligned 8-groups
    x = dppadd<0xB1>(x);    // quad_perm xor1
    x = dppadd<0x4E>(x);    // quad_perm xor2
    x = dppadd<0x141>(x);   // row_half_mirror
    return x;
}
__device__ __forceinline__ float sum16(float x) {  // sum within aligned 16-rows
    x = sum8(x);
    x = dppadd<0x140>(x);   // row_mirror
    return x;
}
__device__ __forceinline__ float expclamp(float t) {
    return __expf(fminf(fmaxf(t, -60.f), 80.f));
}

// ---------------------------------------------------------------------------
// Bucketed CSR build — no per-node global atomics, no random global writes.
// ---------------------------------------------------------------------------
__global__ __launch_bounds__(256) void k_bktcnt(const int* __restrict__ edst,
                                                int* __restrict__ bcnt) {
    __shared__ int h[NBK];
    int t = threadIdx.x;
    if (t < NBK) h[t] = 0;
    __syncthreads();
    int eb = blockIdx.x * EPB;
    #pragma unroll
    for (int k = 0; k < EPB / 256; ++k) {
        int e = eb + k * 256 + t;
        if (e < EE) atomicAdd(&h[edst[e] >> 8], 1);
    }
    __syncthreads();
    if (t < NBK && h[t]) atomicAdd(&bcnt[t], h[t]);
}

__global__ __launch_bounds__(256) void k_bscan(const int* __restrict__ bcnt,
                                               int* __restrict__ bbase,
                                               int* __restrict__ bcur) {
    __shared__ int sm[256];
    int t = threadIdx.x;
    int v = (t < NBK) ? bcnt[t] : 0;
    sm[t] = v;
    __syncthreads();
    for (int o = 1; o < 256; o <<= 1) {
        int a = (t >= o) ? sm[t - o] : 0;
        __syncthreads();
        sm[t] += a;
        __syncthreads();
    }
    if (t < NBK) { int ex = sm[t] - v; bbase[t] = ex; bcur[t] = ex; }
}

__global__ __launch_bounds__(256) void k_bktplace(const int* __restrict__ esrc,
                                                  const int* __restrict__ edst,
                                                  int* __restrict__ bcur,
                                                  uint* __restrict__ ebuf) {
    __shared__ int h[NBK];
    __shared__ int base[NBK];
    int t = threadIdx.x;
    if (t < NBK) h[t] = 0;
    __syncthreads();
    int eb = blockIdx.x * EPB;
    int pk[EPB / 256];   // (bucket<<16)|local_rank per edge
    #pragma unroll
    for (int k = 0; k < EPB / 256; ++k) {
        int e = eb + k * 256 + t;
        pk[k] = -1;
        if (e < EE) {
            int b = edst[e] >> 8;
            int r = atomicAdd(&h[b], 1);
            pk[k] = (b << 16) | r;
        }
    }
    __syncthreads();
    if (t < NBK && h[t]) base[t] = atomicAdd(&bcur[t], h[t]);
    __syncthreads();
    #pragma unroll
    for (int k = 0; k < EPB / 256; ++k) {
        int e = eb + k * 256 + t;
        if (e < EE) {
            int b = pk[k] >> 16;
            int r = pk[k] & 0xFFFF;
            uint dl = (uint)(edst[e] & 255);
            ebuf[base[b] + r] = (dl << 16) | (uint)esrc[e];
        }
    }
}

// one block per bucket: per-node degree + scan + cursor all in LDS.
__global__ __launch_bounds__(256) void k_bktfin(const uint* __restrict__ ebuf,
                                                const int* __restrict__ bbase,
                                                const int* __restrict__ bcnt,
                                                int* __restrict__ rowptr,
                                                int* __restrict__ csrc) {
    __shared__ int deg[256];
    __shared__ int sm[256];
    __shared__ int cur[256];
    const int b = blockIdx.x;
    const int t = threadIdx.x;
    const int eb = bbase[b];
    const int ec = bcnt[b];
    deg[t] = 0;
    __syncthreads();
    for (int k = t; k < ec; k += 256)
        atomicAdd(&deg[ebuf[eb + k] >> 16], 1);
    __syncthreads();
    int v = deg[t];
    sm[t] = v;
    __syncthreads();
    for (int o = 1; o < 256; o <<= 1) {
        int a = (t >= o) ? sm[t - o] : 0;
        __syncthreads();
        sm[t] += a;
        __syncthreads();
    }
    int node = b * 256 + t;
    if (node < NN) rowptr[node + 1] = eb + sm[t];
    if (node == 0) rowptr[0] = 0;
    cur[t] = sm[t] - v;   // exclusive
    __syncthreads();
    for (int k = t; k < ec; k += 256) {
        uint u = ebuf[eb + k];
        int nl = (int)(u >> 16);
        int r = atomicAdd(&cur[nl], 1);
        csrc[eb + r] = (int)(u & 0xFFFFu);
    }
}

// ---------------------------------------------------------------------------
// Weight conversion: W [128 x FOUT] fp32 -> bf16 hi/lo in MFMA-fragment order.
// ---------------------------------------------------------------------------
struct WPack {
    const float* W[8];
    ushort* Th[8];
    ushort* Tl[8];
    int fout[8];
};

__global__ __launch_bounds__(256) void k_conv_w(WPack p) {
    int wi = blockIdx.y;
    int fout = p.fout[wi];
    int total = 128 * fout;
    int i = blockIdx.x * 256 + threadIdx.x;
    if (i >= total) return;
    int k = i / fout;
    int n = i - k * fout;
    float f = p.W[wi][i];
    ushort h = f2bf(f);
    float lo = f - bf2f(h);
    int t = n >> 4, m = n & 15, c = k >> 5, quad = (k >> 3) & 3, j = k & 7;
    int flat = ((((t * 4 + c) * 4 + quad) * 16 + m) << 3) + j;
    p.Th[wi][flat] = h;
    p.Tl[wi][flat] = f2bf(lo);
}

// ---------------------------------------------------------------------------
// Fused split-bf16 MFMA GEMM + attention-dot epilogue.
// 512 thr, B staged ONCE in LDS (global_load_lds), blockIdx.y = t-slice.
// NEW: each block processes 2 row-tiles (rt = bx, bx+GX) with A-prefetch:
// tile-1's A-loads are issued before tile-0's compute so their HBM latency
// hides under tile-0's MFMA+stores. Loop is barrier-free after staging.
// O1 (XR) stored bf16; linear logit parts in fp32 DL/DR.
// ---------------------------------------------------------------------------
template <int FOUT, int NMAT, bool CVT, int TS, int GX>
__global__ __launch_bounds__(512) void k_gemm_fused(
    const float* __restrict__ Xf,
    const ushort* __restrict__ Xh, const ushort* __restrict__ Xl,
    const ushort* __restrict__ T0h, const ushort* __restrict__ T0l, const float* __restrict__ B0,
    const ushort* __restrict__ T1h, const ushort* __restrict__ T1l, const float* __restrict__ B1,
    const ushort* __restrict__ T2h, const ushort* __restrict__ T2l,
    const float* __restrict__ ATT, float* __restrict__ DL, float* __restrict__ DR,
    ushort* __restrict__ O0b, ushort* __restrict__ O1b, float* __restrict__ O2)
{
    constexpr int CH = TS * 2048;                 // ushorts per staged chunk
    constexpr int NTILE = (NN + 127) / 128;       // 391
    __shared__ __align__(16) ushort Bs[NMAT * 2 * CH];

    const int tid  = threadIdx.x;
    const int lane = tid & 63;
    const int wid  = tid >> 6;                    // 0..7
    const int m    = lane & 15;
    const int quad = lane >> 4;
    const int t0   = blockIdx.y * TS;

    // ---- stage B slice into LDS (one 8KB chunk per table) ----
    {
        const ushort* tbls[6] = {T0h, T0l, T1h, T1l, T2h, T2l};
        #pragma unroll
        for (int k = 0; k < 2 * NMAT; ++k) {
            gld_lds16(tbls[k] + (size_t)t0 * 2048 + (size_t)tid * 8,
                      &Bs[k * CH + tid * 8]);
        }
    }

    // A-load: raw issue (no data-dependent math) + cook (CVT only).
    auto issueA = [&](int rt, float4* rf, v8s* ah, v8s* al) {
        int arow = rt * 128 + wid * 16 + m;
        if (arow > NN - 1) arow = NN - 1;
        #pragma unroll
        for (int c = 0; c < 4; ++c) {
            size_t off = (size_t)arow * 128 + c * 32 + quad * 8;
            if constexpr (CVT) {
                rf[c * 2]     = *(const float4*)(Xf + off);
                rf[c * 2 + 1] = *(const float4*)(Xf + off + 4);
            } else {
                ah[c] = *(const v8s*)(Xh + off);
                al[c] = *(const v8s*)(Xl + off);
            }
        }
    };
    auto cookA = [&](const float4* rf, v8s* ah, v8s* al) {
        if constexpr (CVT) {
            #pragma unroll
            for (int c = 0; c < 4; ++c) {
                const float fe[8] = {rf[c*2].x,   rf[c*2].y,   rf[c*2].z,   rf[c*2].w,
                                     rf[c*2+1].x, rf[c*2+1].y, rf[c*2+1].z, rf[c*2+1].w};
                #pragma unroll
                for (int e = 0; e < 8; ++e) {
                    ushort h = f2bf(fe[e]);
                    float lo = fe[e] - bf2f(h);
                    ah[c][e] = (short)h;
                    al[c][e] = (short)(__float_as_uint(lo) >> 16);  // truncate lo
                }
            }
        }
    };

    auto computeTile = [&](int rt, const v8s* ah, const v8s* al) {
        const int row0 = rt * 128 + wid * 16;
        float dp0[4] = {0.f, 0.f, 0.f, 0.f};
        float dp1[4] = {0.f, 0.f, 0.f, 0.f};
        #pragma unroll
        for (int tt = 0; tt < TS; ++tt) {
            const int t = t0 + tt;
            v4f a0 = {0.f, 0.f, 0.f, 0.f};
            v4f a1 = {0.f, 0.f, 0.f, 0.f};
            v4f a2 = {0.f, 0.f, 0.f, 0.f};
            #pragma unroll
            for (int c = 0; c < 4; ++c) {
                const int fo = tt * 2048 + (c * 4 + quad) * 128 + m * 8;
                v8s b0h = *(const v8s*)&Bs[0 * CH + fo];
                v8s b0l = *(const v8s*)&Bs[1 * CH + fo];
                v8s b1h = *(const v8s*)&Bs[2 * CH + fo];
                v8s b1l = *(const v8s*)&Bs[3 * CH + fo];
                a0 = __builtin_amdgcn_mfma_f32_16x16x32_bf16(al[c], b0h, a0, 0, 0, 0);
                a1 = __builtin_amdgcn_mfma_f32_16x16x32_bf16(al[c], b1h, a1, 0, 0, 0);
                a0 = __builtin_amdgcn_mfma_f32_16x16x32_bf16(ah[c], b0l, a0, 0, 0, 0);
                a1 = __builtin_amdgcn_mfma_f32_16x16x32_bf16(ah[c], b1l, a1, 0, 0, 0);
                a0 = __builtin_amdgcn_mfma_f32_16x16x32_bf16(ah[c], b0h, a0, 0, 0, 0);
                a1 = __builtin_amdgcn_mfma_f32_16x16x32_bf16(ah[c], b1h, a1, 0, 0, 0);
                if constexpr (NMAT == 3) {
                    v8s b2h = *(const v8s*)&Bs[4 * CH + fo];
                    v8s b2l = *(const v8s*)&Bs[5 * CH + fo];
                    a2 = __builtin_amdgcn_mfma_f32_16x16x32_bf16(al[c], b2h, a2, 0, 0, 0);
                    a2 = __builtin_amdgcn_mfma_f32_16x16x32_bf16(ah[c], b2l, a2, 0, 0, 0);
                    a2 = __builtin_amdgcn_mfma_f32_16x16x32_bf16(ah[c], b2h, a2, 0, 0, 0);
                }
            }
            const int col = t * 16 + m;
            const float bad0 = B0[col];
            const float bad1 = B1[col];
            const float attc = ATT[col];
            #pragma unroll
            for (int j = 0; j < 4; ++j) {
                float o0v = a0[j] + bad0;
                float o1v = a1[j] + bad1;
                dp0[j] = fmaf(attc, o0v, dp0[j]);
                dp1[j] = fmaf(attc, o1v, dp1[j]);
                int r = row0 + quad * 4 + j;
                if (r < NN) {
                    O0b[(size_t)r * FOUT + col] = f2bf(o0v);
                    O1b[(size_t)r * FOUT + col] = f2bf(o1v);
                    if constexpr (NMAT == 3) O2[(size_t)r * FOUT + col] = a2[j];
                }
            }
            if constexpr (FOUT == 128) {
                if ((t & 1) == 1) {   // head h = t>>1 complete -> reduce + store
                    const int h = t >> 1;
                    #pragma unroll
                    for (int j = 0; j < 4; ++j) {
                        float s0 = sum16(dp0[j]);
                        float s1 = sum16(dp1[j]);
                        int r = row0 + quad * 4 + j;
                        if (m == 0 && r < NN) {
                            DL[(size_t)r * 4 + h] = 0.6f * s0;
                            DR[(size_t)r * 4 + h] = 0.6f * s1;
                        }
                        dp0[j] = 0.f;
                        dp1[j] = 0.f;
                    }
                }
            }
        }
        if constexpr (FOUT == 64) {   // head spans all 4 t -> partial, atomic
            #pragma unroll
            for (int j = 0; j < 4; ++j) {
                float s0 = sum16(dp0[j]);
                float s1 = sum16(dp1[j]);
                int r = row0 + quad * 4 + j;
                if (m == 0 && r < NN) {
                    atomicAdd(&DL[r], 0.6f * s0);
                    atomicAdd(&DR[r], 0.6f * s1);
                }
            }
        }
    };

    const int rt0 = blockIdx.x;
    const int rt1 = blockIdx.x + GX;
    const bool has1 = (rt1 < NTILE);

    float4 rf0[8], rf1[8];                 // CVT raw (DCE'd when !CVT)
    v8s ah0[4], al0[4], ah1[4], al1[4];    // cooked A (ah1/al1 DCE'd when CVT)

    issueA(rt0, rf0, ah0, al0);
    __syncthreads();   // drains global_load_lds (vmcnt) + orders LDS

    if (has1) issueA(rt1, rf1, ah1, al1);  // prefetch tile 1 (overlaps tile-0 compute)

    cookA(rf0, ah0, al0);
    computeTile(rt0, ah0, al0);
    if (has1) {
        if constexpr (CVT) {
            cookA(rf1, ah0, al0);          // reuse cooked regs (rf1 -> ah0/al0)
            computeTile(rt1, ah0, al0);
        } else {
            computeTile(rt1, ah1, al1);
        }
    }
}

// ---------------------------------------------------------------------------
// Aggregation layers 0/1 — 32 lanes/edge, 4 channels/lane, 2-stage pipeline,
// unified masked loop. XR read as bf16 (logit-only use).
//   logit = sum8(0.4*att_c*|xl_c+xr_c|) + DL[src,h] + DR[n,h]
// ---------------------------------------------------------------------------
__global__ __launch_bounds__(256) void k_agg01(const ushort* __restrict__ XLb,
                                               const ushort* __restrict__ XRb,
                                               const float4* __restrict__ RES4,
                                               const float* __restrict__ att,
                                               const float* __restrict__ bias,
                                               const float* __restrict__ DL,
                                               const float* __restrict__ DR,
                                               const int* __restrict__ rowptr,
                                               const int* __restrict__ csrc,
                                               ushort* __restrict__ Hh,
                                               ushort* __restrict__ Hl) {
    const int lane = threadIdx.x & 63;
    const int wid = threadIdx.x >> 6;
    const int n = blockIdx.x * 4 + wid;
    if (n >= NN) return;
    const int beg = rowptr[n];
    const int end = rowptr[n + 1];
    const int e1 = end - 1;
    const int half = lane >> 5;
    const uint j = lane & 31;
    const uint head = j >> 3;

    float4 xr;
    {
        ushort4 u = *(const ushort4*)(XRb + (uint)n * 128u + 4u * j);
        xr.x = bf2f(u.x); xr.y = bf2f(u.y); xr.z = bf2f(u.z); xr.w = bf2f(u.w);
    }
    float4 at = ((const float4*)att)[j];
    at.x *= 0.4f; at.y *= 0.4f; at.z *= 0.4f; at.w *= 0.4f;
    const float dRn = DR[(uint)n * 4u + head];
    float4 s = {0.f, 0.f, 0.f, 0.f};
    float d = 0.f;

#define GL01(I, U0, U1, U2, U3, D0, D1, D2, D3) {              \
    uint sa = (uint)csrc[min((I) + half, e1)];                 \
    uint sb = (uint)csrc[min((I) + 2 + half, e1)];             \
    uint sc = (uint)csrc[min((I) + 4 + half, e1)];             \
    uint sd = (uint)csrc[min((I) + 6 + half, e1)];             \
    U0 = *(const ushort4*)(XLb + sa * 128u + 4u * j);          \
    U1 = *(const ushort4*)(XLb + sb * 128u + 4u * j);          \
    U2 = *(const ushort4*)(XLb + sc * 128u + 4u * j);          \
    U3 = *(const ushort4*)(XLb + sd * 128u + 4u * j);          \
    D0 = DL[sa * 4u + head];                                   \
    D1 = DL[sb * 4u + head];                                   \
    D2 = DL[sc * 4u + head];                                   \
    D3 = DL[sd * 4u + head]; }

#define EDGE01(U, DLV, II) {                                   \
    float v0 = bf2f((U).x), v1 = bf2f((U).y);                  \
    float v2 = bf2f((U).z), v3 = bf2f((U).w);                  \
    float t =      at.x * fabsf(v0 + xr.x);                    \
    t = fmaf(at.y, fabsf(v1 + xr.y), t);                       \
    t = fmaf(at.z, fabsf(v2 + xr.z), t);                       \
    t = fmaf(at.w, fabsf(v3 + xr.w), t);                       \
    float p = expclamp(sum8(t) + (DLV) + dRn);                 \
    p = ((II) < end) ? p : 0.f;                                \
    d += p;                                                    \
    s.x = fmaf(p, v0, s.x); s.y = fmaf(p, v1, s.y);            \
    s.z = fmaf(p, v2, s.z); s.w = fmaf(p, v3, s.w); }

    if (beg < end) {
        ushort4 cu0, cu1, cu2, cu3;
        float cd0, cd1, cd2, cd3;
        GL01(beg, cu0, cu1, cu2, cu3, cd0, cd1, cd2, cd3)
        for (int i = beg; i < end; i += 8) {
            ushort4 nu0, nu1, nu2, nu3;
            float nd0, nd1, nd2, nd3;
            GL01(i + 8, nu0, nu1, nu2, nu3, nd0, nd1, nd2, nd3)
            EDGE01(cu0, cd0, i + half)
            EDGE01(cu1, cd1, i + 2 + half)
            EDGE01(cu2, cd2, i + 4 + half)
            EDGE01(cu3, cd3, i + 6 + half)
            cu0 = nu0; cu1 = nu1; cu2 = nu2; cu3 = nu3;
            cd0 = nd0; cd1 = nd1; cd2 = nd2; cd3 = nd3;
        }
    }
#undef GL01
#undef EDGE01

    d   += __shfl_xor(d, 32);
    s.x += __shfl_xor(s.x, 32);
    s.y += __shfl_xor(s.y, 32);
    s.z += __shfl_xor(s.z, 32);
    s.w += __shfl_xor(s.w, 32);

    if (half == 0) {
        float inv = (d > 0.f) ? 1.f / d : 0.f;
        float4 rv = RES4[(uint)n * 32u + j];
        float4 bv = ((const float4*)bias)[j];
        float o0 = fmaf(s.x, inv, rv.x + bv.x);
        float o1 = fmaf(s.y, inv, rv.y + bv.y);
        float o2 = fmaf(s.z, inv, rv.z + bv.z);
        float o3 = fmaf(s.w, inv, rv.w + bv.w);
        o0 = o0 > 0.f ? o0 : __expf(o0) - 1.f;   // ELU
        o1 = o1 > 0.f ? o1 : __expf(o1) - 1.f;
        o2 = o2 > 0.f ? o2 : __expf(o2) - 1.f;
        o3 = o3 > 0.f ? o3 : __expf(o3) - 1.f;
        ushort4 h, l;
        h.x = f2bf(o0); l.x = f2bf(o0 - bf2f(h.x));
        h.y = f2bf(o1); l.y = f2bf(o1 - bf2f(h.y));
        h.z = f2bf(o2); l.z = f2bf(o2 - bf2f(h.z));
        h.w = f2bf(o3); l.w = f2bf(o3 - bf2f(h.w));
        *(ushort4*)(Hh + (uint)n * 128u + 4u * j) = h;
        *(ushort4*)(Hl + (uint)n * 128u + 4u * j) = l;
    }
}

// ---------------------------------------------------------------------------
// Aggregation layer 2 — F=64, H=1, 16 lanes/edge, 4 channels/lane,
// 2-stage pipeline, unified masked loop. XR read as bf16.
// ---------------------------------------------------------------------------
__global__ __launch_bounds__(256) void k_agg2(const ushort* __restrict__ XLb,
                                              const ushort* __restrict__ XRb,
                                              const float* __restrict__ att,
                                              const float* __restrict__ bias,
                                              const float* __restrict__ DL,
                                              const float* __restrict__ DR,
                                              const int* __restrict__ rowptr,
                                              const int* __restrict__ csrc,
                                              float* __restrict__ OUT) {
    const int lane = threadIdx.x & 63;
    const int wid = threadIdx.x >> 6;
    const int n = blockIdx.x * 4 + wid;
    if (n >= NN) return;
    const int beg = rowptr[n];
    const int end = rowptr[n + 1];
    const int e1 = end - 1;
    const int q = lane >> 4;
    const uint jj = lane & 15;

    float4 xr;
    {
        ushort4 u = *(const ushort4*)(XRb + (uint)n * 64u + 4u * jj);
        xr.x = bf2f(u.x); xr.y = bf2f(u.y); xr.z = bf2f(u.z); xr.w = bf2f(u.w);
    }
    float4 at = ((const float4*)att)[jj];
    at.x *= 0.4f; at.y *= 0.4f; at.z *= 0.4f; at.w *= 0.4f;
    const float dRn = DR[n];
    float4 s = {0.f, 0.f, 0.f, 0.f};
    float d = 0.f;

#define GL2(I, U0, U1, D0, D1) {                               \
    uint sa = (uint)csrc[min((I) + q, e1)];                    \
    uint sb = (uint)csrc[min((I) + 4 + q, e1)];                \
    U0 = *(const ushort4*)(XLb + sa * 64u + 4u * jj);          \
    U1 = *(const ushort4*)(XLb + sb * 64u + 4u * jj);          \
    D0 = DL[sa];                                               \
    D1 = DL[sb]; }

#define EDGE2(U, DLV, II) {                                    \
    float v0 = bf2f((U).x), v1 = bf2f((U).y);                  \
    float v2 = bf2f((U).z), v3 = bf2f((U).w);                  \
    float t =      at.x * fabsf(v0 + xr.x);                    \
    t = fmaf(at.y, fabsf(v1 + xr.y), t);                       \
    t = fmaf(at.z, fabsf(v2 + xr.z), t);                       \
    t = fmaf(at.w, fabsf(v3 + xr.w), t);                       \
    float p = expclamp(sum16(t) + (DLV) + dRn);                \
    p = ((II) < end) ? p : 0.f;                                \
    d += p;                                                    \
    s.x = fmaf(p, v0, s.x); s.y = fmaf(p, v1, s.y);            \
    s.z = fmaf(p, v2, s.z); s.w = fmaf(p, v3, s.w); }

    if (beg < end) {
        ushort4 cu0, cu1;
        float cd0, cd1;
        GL2(beg, cu0, cu1, cd0, cd1)
        for (int i = beg; i < end; i += 8) {
            ushort4 nu0, nu1;
            float nd0, nd1;
            GL2(i + 8, nu0, nu1, nd0, nd1)
            EDGE2(cu0, cd0, i + q)
            EDGE2(cu1, cd1, i + 4 + q)
            cu0 = nu0; cu1 = nu1;
            cd0 = nd0; cd1 = nd1;
        }
    }
#undef GL2
#undef EDGE2

    d   += __shfl_xor(d, 16);   d   += __shfl_xor(d, 32);
    s.x += __shfl_xor(s.x, 16); s.x += __shfl_xor(s.x, 32);
    s.y += __shfl_xor(s.y, 16); s.y += __shfl_xor(s.y, 32);
    s.z += __shfl_xor(s.z, 16); s.z += __shfl_xor(s.z, 32);
    s.w += __shfl_xor(s.w, 16); s.w += __shfl_xor(s.w, 32);

    if (lane < 16) {
        float inv = (d > 0.f) ? 1.f / d : 0.f;
        float4 bv = ((const float4*)bias)[jj];
        float4 o;
        o.x = fmaf(s.x, inv, bv.x);
        o.y = fmaf(s.y, inv, bv.y);
        o.z = fmaf(s.z, inv, bv.z);
        o.w = fmaf(s.w, inv, bv.w);
        *(float4*)(OUT + (uint)n * 64u + 4u * jj) = o;
    }
}

// ---------------------------------------------------------------------------
extern "C" void kernel_launch(void* const* d_in, const int* in_sizes, int n_in,
                              void* d_out, int out_size, void* d_ws, size_t ws_size,
                              hipStream_t stream) {
    const float* x    = (const float*)d_in[0];
    const int*   ei   = (const int*)d_in[1];
    const int*   esrc = ei;
    const int*   edst = ei + EE;

    const float* Wl0 = (const float*)d_in[2];
    const float* bl0 = (const float*)d_in[3];
    const float* Wr0 = (const float*)d_in[4];
    const float* br0 = (const float*)d_in[5];
    const float* at0 = (const float*)d_in[6];
    const float* b0  = (const float*)d_in[7];
    const float* rs0 = (const float*)d_in[8];
    const float* Wl1 = (const float*)d_in[9];
    const float* bl1 = (const float*)d_in[10];
    const float* Wr1 = (const float*)d_in[11];
    const float* br1 = (const float*)d_in[12];
    const float* at1 = (const float*)d_in[13];
    const float* b1  = (const float*)d_in[14];
    const float* rs1 = (const float*)d_in[15];
    const float* Wl2 = (const float*)d_in[16];
    const float* bl2 = (const float*)d_in[17];
    const float* Wr2 = (const float*)d_in[18];
    const float* br2 = (const float*)d_in[19];
    const float* at2 = (const float*)d_in[20];
    const float* b2  = (const float*)d_in[21];

    float* out = (float*)d_out;

    // --- workspace layout ---
    ushort* XLb = (ushort*)d_ws;               // [NN*128] bf16 (gather payload)
    ushort* XRb = XLb + (size_t)NN * 128;             // [NN*128] bf16 (XR)
    float* RES = (float*)(XRb + (size_t)NN * 128);    // [NN*128] fp32
    ushort* Xh = (ushort*)(RES + (size_t)NN * 128);   // [NN*128] bf16-hi (H)
    ushort* Xl_ = Xh + (size_t)NN * 128;              // [NN*128] bf16-lo (H)
    float* DLarr = (float*)(Xl_ + (size_t)NN * 128);  // [NN*4] fp32 dotL
    float* DRarr = DLarr + (size_t)NN * 4;            // [NN*4] fp32 dotR
    ushort* Wth = (ushort*)(DRarr + (size_t)NN * 4);
    const int wsz[8] = {16384, 16384, 16384, 16384, 16384, 16384, 8192, 8192};
    ushort* th[8]; ushort* tl[8];
    {
        ushort* p = Wth;
        for (int i = 0; i < 8; ++i) { th[i] = p; p += wsz[i]; }
        for (int i = 0; i < 8; ++i) { tl[i] = p; p += wsz[i]; }
    }
    int* bcnt   = (int*)(Wth + 2 * (6 * 16384 + 2 * 8192));  // 256 (memset)
    int* bbase  = bcnt + 256;                  // 256
    int* bcur   = bbase + 256;                 // 256
    int* rowptr = bcur + 256;                  // NN+1
    int* csrc   = rowptr + (NN + 1);           // EE
    uint* ebuf  = (uint*)(csrc + EE);          // EE

    // --- bucketed CSR build (graph identical across layers) ---
    hipMemsetAsync(bcnt, 0, 256 * sizeof(int), stream);
    const int ebk = (EE + EPB - 1) / EPB;      // 196
    k_bktcnt<<<ebk, 256, 0, stream>>>(edst, bcnt);
    k_bscan<<<1, 256, 0, stream>>>(bcnt, bbase, bcur);
    k_bktplace<<<ebk, 256, 0, stream>>>(esrc, edst, bcur, ebuf);
    k_bktfin<<<NBK, 256, 0, stream>>>(ebuf, bbase, bcnt, rowptr, csrc);

    // --- weight conversion ---
    WPack wp;
    const float* Ws[8] = {Wl0, Wr0, rs0, Wl1, Wr1, rs1, Wl2, Wr2};
    const int fouts[8] = {128, 128, 128, 128, 128, 128, 64, 64};
    for (int i = 0; i < 8; ++i) { wp.W[i] = Ws[i]; wp.Th[i] = th[i]; wp.Tl[i] = tl[i]; wp.fout[i] = fouts[i]; }
    k_conv_w<<<dim3(64, 8), 256, 0, stream>>>(wp);

    const int agg_grid = (NN + 3) / 4;

    // --- Layer 0 (A from fp32 x; 3 weight mats fused; 2 row-tiles/block) ---
    k_gemm_fused<128, 3, true, 2, 196><<<dim3(196, 4), 512, 0, stream>>>(x, nullptr, nullptr,
        th[0], tl[0], bl0, th[1], tl[1], br0, th[2], tl[2], at0, DLarr, DRarr, XLb, XRb, RES);
    k_agg01<<<agg_grid, 256, 0, stream>>>(XLb, XRb, (const float4*)RES,
        at0, b0, DLarr, DRarr, rowptr, csrc, Xh, Xl_);

    // --- Layer 1 ---
    k_gemm_fused<128, 3, false, 2, 196><<<dim3(196, 4), 512, 0, stream>>>(nullptr, Xh, Xl_,
        th[3], tl[3], bl1, th[4], tl[4], br1, th[5], tl[5], at1, DLarr, DRarr, XLb, XRb, RES);
    k_agg01<<<agg_grid, 256, 0, stream>>>(XLb, XRb, (const float4*)RES,
        at1, b1, DLarr, DRarr, rowptr, csrc, Xh, Xl_);

    // --- Layer 2 (heads=1, C=64; single tile/block — unchanged behavior) ---
    hipMemsetAsync(DLarr, 0, NN * sizeof(float), stream);
    hipMemsetAsync(DRarr, 0, NN * sizeof(float), stream);
    k_gemm_fused<64, 2, false, 2, 391><<<dim3(391, 2), 512, 0, stream>>>(nullptr, Xh, Xl_,
        th[6], tl[6], bl2, th[7], tl[7], br2, nullptr, nullptr, at2, DLarr, DRarr, XLb, XRb, nullptr);
    k_agg2<<<agg_grid, 256, 0, stream>>>(XLb, XRb, at2, b2, DLarr, DRarr, rowptr, csrc, out);
}

// Round 10
// 356.182 us; speedup vs baseline: 1.0642x; 1.0642x over previous
//
#include <hip/hip_runtime.h>
#include <math.h>

// Problem constants (from reference)
#define NN 50000
#define EE 800000
#define NBK 196    // node buckets (256 nodes each): ceil(50000/256)
#define EPB 4096   // edges per pass-A block: ceil(800000/4096) = 196 blocks

typedef short v8s __attribute__((ext_vector_type(8)));
typedef float v4f __attribute__((ext_vector_type(4)));

__device__ __forceinline__ ushort f2bf(float f) {
    uint u = __float_as_uint(f);
    uint r = (u + 0x7fffu + ((u >> 16) & 1u)) >> 16;
    return (ushort)r;
}
__device__ __forceinline__ float bf2f(ushort h) {
    return __uint_as_float(((uint)h) << 16);
}

// async global->LDS, 16B per lane (dest = wave-uniform base + lane*16)
__device__ __forceinline__ void gld_lds16(const void* g, void* l) {
    __builtin_amdgcn_global_load_lds(
        (const __attribute__((address_space(1))) void*)g,
        (__attribute__((address_space(3))) void*)l, 16, 0, 0);
}

// DPP partial reductions (no LDS pipe).
template <int CTRL>
__device__ __forceinline__ float dppadd(float x) {
    int y = __builtin_amdgcn_update_dpp(0, __float_as_int(x), CTRL, 0xf, 0xf, true);
    return x + __int_as_float(y);
}
__device__ __forceinline__ float sum8(float x) {   // sum within aligned 8-groups
    x = dppadd<0xB1>(x);    // quad_perm xor1
    x = dppadd<0x4E>(x);    // quad_perm xor2
    x = dppadd<0x141>(x);   // row_half_mirror
    return x;
}
__device__ __forceinline__ float sum16(float x) {  // sum within aligned 16-rows
    x = sum8(x);
    x = dppadd<0x140>(x);   // row_mirror
    return x;
}
__device__ __forceinline__ float expclamp(float t) {
    return __expf(fminf(fmaxf(t, -60.f), 80.f));
}

// ---------------------------------------------------------------------------
// Bucketed CSR build — no per-node global atomics, no random global writes.
// ---------------------------------------------------------------------------
__global__ __launch_bounds__(256) void k_bktcnt(const int* __restrict__ edst,
                                                int* __restrict__ bcnt) {
    __shared__ int h[NBK];
    int t = threadIdx.x;
    if (t < NBK) h[t] = 0;
    __syncthreads();
    int eb = blockIdx.x * EPB;
    #pragma unroll
    for (int k = 0; k < EPB / 256; ++k) {
        int e = eb + k * 256 + t;
        if (e < EE) atomicAdd(&h[edst[e] >> 8], 1);
    }
    __syncthreads();
    if (t < NBK && h[t]) atomicAdd(&bcnt[t], h[t]);
}

__global__ __launch_bounds__(256) void k_bscan(const int* __restrict__ bcnt,
                                               int* __restrict__ bbase,
                                               int* __restrict__ bcur) {
    __shared__ int sm[256];
    int t = threadIdx.x;
    int v = (t < NBK) ? bcnt[t] : 0;
    sm[t] = v;
    __syncthreads();
    for (int o = 1; o < 256; o <<= 1) {
        int a = (t >= o) ? sm[t - o] : 0;
        __syncthreads();
        sm[t] += a;
        __syncthreads();
    }
    if (t < NBK) { int ex = sm[t] - v; bbase[t] = ex; bcur[t] = ex; }
}

__global__ __launch_bounds__(256) void k_bktplace(const int* __restrict__ esrc,
                                                  const int* __restrict__ edst,
                                                  int* __restrict__ bcur,
                                                  uint* __restrict__ ebuf) {
    __shared__ int h[NBK];
    __shared__ int base[NBK];
    int t = threadIdx.x;
    if (t < NBK) h[t] = 0;
    __syncthreads();
    int eb = blockIdx.x * EPB;
    int pk[EPB / 256];   // (bucket<<16)|local_rank per edge
    #pragma unroll
    for (int k = 0; k < EPB / 256; ++k) {
        int e = eb + k * 256 + t;
        pk[k] = -1;
        if (e < EE) {
            int b = edst[e] >> 8;
            int r = atomicAdd(&h[b], 1);
            pk[k] = (b << 16) | r;
        }
    }
    __syncthreads();
    if (t < NBK && h[t]) base[t] = atomicAdd(&bcur[t], h[t]);
    __syncthreads();
    #pragma unroll
    for (int k = 0; k < EPB / 256; ++k) {
        int e = eb + k * 256 + t;
        if (e < EE) {
            int b = pk[k] >> 16;
            int r = pk[k] & 0xFFFF;
            uint dl = (uint)(edst[e] & 255);
            ebuf[base[b] + r] = (dl << 16) | (uint)esrc[e];
        }
    }
}

// one block per bucket: per-node degree + scan + cursor all in LDS.
__global__ __launch_bounds__(256) void k_bktfin(const uint* __restrict__ ebuf,
                                                const int* __restrict__ bbase,
                                                const int* __restrict__ bcnt,
                                                int* __restrict__ rowptr,
                                                int* __restrict__ csrc) {
    __shared__ int deg[256];
    __shared__ int sm[256];
    __shared__ int cur[256];
    const int b = blockIdx.x;
    const int t = threadIdx.x;
    const int eb = bbase[b];
    const int ec = bcnt[b];
    deg[t] = 0;
    __syncthreads();
    for (int k = t; k < ec; k += 256)
        atomicAdd(&deg[ebuf[eb + k] >> 16], 1);
    __syncthreads();
    int v = deg[t];
    sm[t] = v;
    __syncthreads();
    for (int o = 1; o < 256; o <<= 1) {
        int a = (t >= o) ? sm[t - o] : 0;
        __syncthreads();
        sm[t] += a;
        __syncthreads();
    }
    int node = b * 256 + t;
    if (node < NN) rowptr[node + 1] = eb + sm[t];
    if (node == 0) rowptr[0] = 0;
    cur[t] = sm[t] - v;   // exclusive
    __syncthreads();
    for (int k = t; k < ec; k += 256) {
        uint u = ebuf[eb + k];
        int nl = (int)(u >> 16);
        int r = atomicAdd(&cur[nl], 1);
        csrc[eb + r] = (int)(u & 0xFFFFu);
    }
}

// ---------------------------------------------------------------------------
// Weight conversion: W [128 x FOUT] fp32 -> bf16 hi/lo in MFMA-fragment order.
// ---------------------------------------------------------------------------
struct WPack {
    const float* W[8];
    ushort* Th[8];
    ushort* Tl[8];
    int fout[8];
};

__global__ __launch_bounds__(256) void k_conv_w(WPack p) {
    int wi = blockIdx.y;
    int fout = p.fout[wi];
    int total = 128 * fout;
    int i = blockIdx.x * 256 + threadIdx.x;
    if (i >= total) return;
    int k = i / fout;
    int n = i - k * fout;
    float f = p.W[wi][i];
    ushort h = f2bf(f);
    float lo = f - bf2f(h);
    int t = n >> 4, m = n & 15, c = k >> 5, quad = (k >> 3) & 3, j = k & 7;
    int flat = ((((t * 4 + c) * 4 + quad) * 16 + m) << 3) + j;
    p.Th[wi][flat] = h;
    p.Tl[wi][flat] = f2bf(lo);
}

// ---------------------------------------------------------------------------
// Fused split-bf16 MFMA GEMM + attention-dot epilogue, split-K staging:
// K (c=0..3) is staged in TWO halves into a 24KB (NMAT=3) / 16KB (NMAT=2)
// single LDS buffer — half the round-8 LDS -> ~2x resident blocks/CU ->
// more outstanding requests -> higher achieved BW. Accumulators persist in
// VGPRs across halves. Layout: each K-half of a t-column is a contiguous
// 1024-ushort chunk in the fragment-ordered table, so staging stays linear.
// TS must be 2. O1 (XR) stored bf16; linear logit parts in fp32 DL/DR.
// ---------------------------------------------------------------------------
template <int FOUT, int NMAT, bool CVT, int TS>
__global__ __launch_bounds__(512) void k_gemm_fused(
    const float* __restrict__ Xf,
    const ushort* __restrict__ Xh, const ushort* __restrict__ Xl,
    const ushort* __restrict__ T0h, const ushort* __restrict__ T0l, const float* __restrict__ B0,
    const ushort* __restrict__ T1h, const ushort* __restrict__ T1l, const float* __restrict__ B1,
    const ushort* __restrict__ T2h, const ushort* __restrict__ T2l,
    const float* __restrict__ ATT, float* __restrict__ DL, float* __restrict__ DR,
    ushort* __restrict__ O0b, ushort* __restrict__ O1b, float* __restrict__ O2)
{
    static_assert(TS == 2, "split-K staging assumes TS==2");
    // region per table = TS*1024 = 2048 ushorts; total = NMAT*2 * 2048
    __shared__ __align__(16) ushort Bs[NMAT * 4096];

    const int tid  = threadIdx.x;
    const int lane = tid & 63;
    const int wid  = tid >> 6;                    // 0..7
    const int m    = lane & 15;
    const int quad = lane >> 4;
    const int row0 = blockIdx.x * 128 + wid * 16;
    const int t0   = blockIdx.y * TS;

    const ushort* tb0 = T0h; const ushort* tb1 = T0l;
    const ushort* tb2 = T1h; const ushort* tb3 = T1l;
    const ushort* tb4 = T2h; const ushort* tb5 = T2l;

    // Stage K-half h: per table, per tt, the half is tbl+(t0+tt)*2048+h*1024,
    // 1024 ushorts contiguous. 2 tables per round (tid<256 / tid>=256).
    auto stageHalf = [&](int h) {
        const int cidx = (tid & 255) * 8;      // ushort offset in 2048-region
        const int tt   = cidx >> 10;
        const int rem  = cidx & 1023;
        const size_t srcoff = (size_t)(t0 + tt) * 2048 + h * 1024 + rem;
        {
            const ushort* tp = (tid < 256) ? tb0 : tb1;
            gld_lds16(tp + srcoff, &Bs[0 * 4096 + tid * 8]);
        }
        {
            const ushort* tp = (tid < 256) ? tb2 : tb3;
            gld_lds16(tp + srcoff, &Bs[1 * 4096 + tid * 8]);
        }
        if constexpr (NMAT == 3) {
            const ushort* tp = (tid < 256) ? tb4 : tb5;
            gld_lds16(tp + srcoff, &Bs[2 * 4096 + tid * 8]);
        }
    };

    // ---- A fragments (per-wave rows), loaded once ----
    v8s ah[4], al[4];
    {
        int arow = row0 + m;
        if (arow > NN - 1) arow = NN - 1;
        #pragma unroll
        for (int c = 0; c < 4; ++c) {
            size_t off = (size_t)arow * 128 + c * 32 + quad * 8;
            if constexpr (CVT) {
                float4 f0 = *(const float4*)(Xf + off);
                float4 f1 = *(const float4*)(Xf + off + 4);
                const float fe[8] = {f0.x, f0.y, f0.z, f0.w, f1.x, f1.y, f1.z, f1.w};
                #pragma unroll
                for (int e = 0; e < 8; ++e) {
                    ushort hh = f2bf(fe[e]);
                    float lo = fe[e] - bf2f(hh);
                    ah[c][e] = (short)hh;
                    al[c][e] = (short)(__float_as_uint(lo) >> 16);  // truncate lo
                }
            } else {
                ah[c] = *(const v8s*)(Xh + off);
                al[c] = *(const v8s*)(Xl + off);
            }
        }
    }

    v4f a0[TS], a1[TS], a2[TS];
    #pragma unroll
    for (int tt = 0; tt < TS; ++tt) {
        a0[tt] = v4f{0.f, 0.f, 0.f, 0.f};
        a1[tt] = v4f{0.f, 0.f, 0.f, 0.f};
        a2[tt] = v4f{0.f, 0.f, 0.f, 0.f};
    }

    stageHalf(0);
    __syncthreads();   // staging of half 0 visible

    #pragma unroll
    for (int h = 0; h < 2; ++h) {
        if (h == 1) {
            __syncthreads();   // all ds_reads of half 0 done
            stageHalf(1);
            __syncthreads();   // staging of half 1 visible
        }
        #pragma unroll
        for (int tt = 0; tt < TS; ++tt) {
            #pragma unroll
            for (int lc = 0; lc < 2; ++lc) {
                const int c = 2 * h + lc;      // global K-quarter
                const int fo = tt * 1024 + (lc * 4 + quad) * 128 + m * 8;
                v8s b0h = *(const v8s*)&Bs[0 * 2048 + fo];
                v8s b0l = *(const v8s*)&Bs[1 * 2048 + fo];
                v8s b1h = *(const v8s*)&Bs[2 * 2048 + fo];
                v8s b1l = *(const v8s*)&Bs[3 * 2048 + fo];
                a0[tt] = __builtin_amdgcn_mfma_f32_16x16x32_bf16(al[c], b0h, a0[tt], 0, 0, 0);
                a1[tt] = __builtin_amdgcn_mfma_f32_16x16x32_bf16(al[c], b1h, a1[tt], 0, 0, 0);
                a0[tt] = __builtin_amdgcn_mfma_f32_16x16x32_bf16(ah[c], b0l, a0[tt], 0, 0, 0);
                a1[tt] = __builtin_amdgcn_mfma_f32_16x16x32_bf16(ah[c], b1l, a1[tt], 0, 0, 0);
                a0[tt] = __builtin_amdgcn_mfma_f32_16x16x32_bf16(ah[c], b0h, a0[tt], 0, 0, 0);
                a1[tt] = __builtin_amdgcn_mfma_f32_16x16x32_bf16(ah[c], b1h, a1[tt], 0, 0, 0);
                if constexpr (NMAT == 3) {
                    v8s b2h = *(const v8s*)&Bs[4 * 2048 + fo];
                    v8s b2l = *(const v8s*)&Bs[5 * 2048 + fo];
                    a2[tt] = __builtin_amdgcn_mfma_f32_16x16x32_bf16(al[c], b2h, a2[tt], 0, 0, 0);
                    a2[tt] = __builtin_amdgcn_mfma_f32_16x16x32_bf16(ah[c], b2l, a2[tt], 0, 0, 0);
                    a2[tt] = __builtin_amdgcn_mfma_f32_16x16x32_bf16(ah[c], b2h, a2[tt], 0, 0, 0);
                }
            }
        }
    }

    // ---- epilogue: bias, dot partials, stores ----
    float dp0[4] = {0.f, 0.f, 0.f, 0.f};
    float dp1[4] = {0.f, 0.f, 0.f, 0.f};
    #pragma unroll
    for (int tt = 0; tt < TS; ++tt) {
        const int t = t0 + tt;
        const int col = t * 16 + m;
        const float bad0 = B0[col];
        const float bad1 = B1[col];
        const float attc = ATT[col];
        #pragma unroll
        for (int j = 0; j < 4; ++j) {
            float o0v = a0[tt][j] + bad0;
            float o1v = a1[tt][j] + bad1;
            dp0[j] = fmaf(attc, o0v, dp0[j]);
            dp1[j] = fmaf(attc, o1v, dp1[j]);
            int r = row0 + quad * 4 + j;
            if (r < NN) {
                O0b[(size_t)r * FOUT + col] = f2bf(o0v);
                O1b[(size_t)r * FOUT + col] = f2bf(o1v);
                if constexpr (NMAT == 3) O2[(size_t)r * FOUT + col] = a2[tt][j];
            }
        }
        if constexpr (FOUT == 128) {
            if ((t & 1) == 1) {   // head hd = t>>1 complete -> reduce + store
                const int hd = t >> 1;
                #pragma unroll
                for (int j = 0; j < 4; ++j) {
                    float s0 = sum16(dp0[j]);
                    float s1 = sum16(dp1[j]);
                    int r = row0 + quad * 4 + j;
                    if (m == 0 && r < NN) {
                        DL[(size_t)r * 4 + hd] = 0.6f * s0;
                        DR[(size_t)r * 4 + hd] = 0.6f * s1;
                    }
                    dp0[j] = 0.f;
                    dp1[j] = 0.f;
                }
            }
        }
    }
    if constexpr (FOUT == 64) {   // head spans all 4 t -> partial, atomic
        #pragma unroll
        for (int j = 0; j < 4; ++j) {
            float s0 = sum16(dp0[j]);
            float s1 = sum16(dp1[j]);
            int r = row0 + quad * 4 + j;
            if (m == 0 && r < NN) {
                atomicAdd(&DL[r], 0.6f * s0);
                atomicAdd(&DR[r], 0.6f * s1);
            }
        }
    }
}

// ---------------------------------------------------------------------------
// Aggregation layers 0/1 — 32 lanes/edge, 4 channels/lane, 2-stage pipeline,
// unified masked loop. XR read as bf16 (logit-only use).
//   logit = sum8(0.4*att_c*|xl_c+xr_c|) + DL[src,h] + DR[n,h]
// ---------------------------------------------------------------------------
__global__ __launch_bounds__(256) void k_agg01(const ushort* __restrict__ XLb,
                                               const ushort* __restrict__ XRb,
                                               const float4* __restrict__ RES4,
                                               const float* __restrict__ att,
                                               const float* __restrict__ bias,
                                               const float* __restrict__ DL,
                                               const float* __restrict__ DR,
                                               const int* __restrict__ rowptr,
                                               const int* __restrict__ csrc,
                                               ushort* __restrict__ Hh,
                                               ushort* __restrict__ Hl) {
    const int lane = threadIdx.x & 63;
    const int wid = threadIdx.x >> 6;
    const int n = blockIdx.x * 4 + wid;
    if (n >= NN) return;
    const int beg = rowptr[n];
    const int end = rowptr[n + 1];
    const int e1 = end - 1;
    const int half = lane >> 5;
    const uint j = lane & 31;
    const uint head = j >> 3;

    float4 xr;
    {
        ushort4 u = *(const ushort4*)(XRb + (uint)n * 128u + 4u * j);
        xr.x = bf2f(u.x); xr.y = bf2f(u.y); xr.z = bf2f(u.z); xr.w = bf2f(u.w);
    }
    float4 at = ((const float4*)att)[j];
    at.x *= 0.4f; at.y *= 0.4f; at.z *= 0.4f; at.w *= 0.4f;
    const float dRn = DR[(uint)n * 4u + head];
    float4 s = {0.f, 0.f, 0.f, 0.f};
    float d = 0.f;

#define GL01(I, U0, U1, U2, U3, D0, D1, D2, D3) {              \
    uint sa = (uint)csrc[min((I) + half, e1)];                 \
    uint sb = (uint)csrc[min((I) + 2 + half, e1)];             \
    uint sc = (uint)csrc[min((I) + 4 + half, e1)];             \
    uint sd = (uint)csrc[min((I) + 6 + half, e1)];             \
    U0 = *(const ushort4*)(XLb + sa * 128u + 4u * j);          \
    U1 = *(const ushort4*)(XLb + sb * 128u + 4u * j);          \
    U2 = *(const ushort4*)(XLb + sc * 128u + 4u * j);          \
    U3 = *(const ushort4*)(XLb + sd * 128u + 4u * j);          \
    D0 = DL[sa * 4u + head];                                   \
    D1 = DL[sb * 4u + head];                                   \
    D2 = DL[sc * 4u + head];                                   \
    D3 = DL[sd * 4u + head]; }

#define EDGE01(U, DLV, II) {                                   \
    float v0 = bf2f((U).x), v1 = bf2f((U).y);                  \
    float v2 = bf2f((U).z), v3 = bf2f((U).w);                  \
    float t =      at.x * fabsf(v0 + xr.x);                    \
    t = fmaf(at.y, fabsf(v1 + xr.y), t);                       \
    t = fmaf(at.z, fabsf(v2 + xr.z), t);                       \
    t = fmaf(at.w, fabsf(v3 + xr.w), t);                       \
    float p = expclamp(sum8(t) + (DLV) + dRn);                 \
    p = ((II) < end) ? p : 0.f;                                \
    d += p;                                                    \
    s.x = fmaf(p, v0, s.x); s.y = fmaf(p, v1, s.y);            \
    s.z = fmaf(p, v2, s.z); s.w = fmaf(p, v3, s.w); }

    if (beg < end) {
        ushort4 cu0, cu1, cu2, cu3;
        float cd0, cd1, cd2, cd3;
        GL01(beg, cu0, cu1, cu2, cu3, cd0, cd1, cd2, cd3)
        for (int i = beg; i < end; i += 8) {
            ushort4 nu0, nu1, nu2, nu3;
            float nd0, nd1, nd2, nd3;
            GL01(i + 8, nu0, nu1, nu2, nu3, nd0, nd1, nd2, nd3)
            EDGE01(cu0, cd0, i + half)
            EDGE01(cu1, cd1, i + 2 + half)
            EDGE01(cu2, cd2, i + 4 + half)
            EDGE01(cu3, cd3, i + 6 + half)
            cu0 = nu0; cu1 = nu1; cu2 = nu2; cu3 = nu3;
            cd0 = nd0; cd1 = nd1; cd2 = nd2; cd3 = nd3;
        }
    }
#undef GL01
#undef EDGE01

    d   += __shfl_xor(d, 32);
    s.x += __shfl_xor(s.x, 32);
    s.y += __shfl_xor(s.y, 32);
    s.z += __shfl_xor(s.z, 32);
    s.w += __shfl_xor(s.w, 32);

    if (half == 0) {
        float inv = (d > 0.f) ? 1.f / d : 0.f;
        float4 rv = RES4[(uint)n * 32u + j];
        float4 bv = ((const float4*)bias)[j];
        float o0 = fmaf(s.x, inv, rv.x + bv.x);
        float o1 = fmaf(s.y, inv, rv.y + bv.y);
        float o2 = fmaf(s.z, inv, rv.z + bv.z);
        float o3 = fmaf(s.w, inv, rv.w + bv.w);
        o0 = o0 > 0.f ? o0 : __expf(o0) - 1.f;   // ELU
        o1 = o1 > 0.f ? o1 : __expf(o1) - 1.f;
        o2 = o2 > 0.f ? o2 : __expf(o2) - 1.f;
        o3 = o3 > 0.f ? o3 : __expf(o3) - 1.f;
        ushort4 h, l;
        h.x = f2bf(o0); l.x = f2bf(o0 - bf2f(h.x));
        h.y = f2bf(o1); l.y = f2bf(o1 - bf2f(h.y));
        h.z = f2bf(o2); l.z = f2bf(o2 - bf2f(h.z));
        h.w = f2bf(o3); l.w = f2bf(o3 - bf2f(h.w));
        *(ushort4*)(Hh + (uint)n * 128u + 4u * j) = h;
        *(ushort4*)(Hl + (uint)n * 128u + 4u * j) = l;
    }
}

// ---------------------------------------------------------------------------
// Aggregation layer 2 — F=64, H=1, 16 lanes/edge, 4 channels/lane,
// 2-stage pipeline, unified masked loop. XR read as bf16.
// ---------------------------------------------------------------------------
__global__ __launch_bounds__(256) void k_agg2(const ushort* __restrict__ XLb,
                                              const ushort* __restrict__ XRb,
                                              const float* __restrict__ att,
                                              const float* __restrict__ bias,
                                              const float* __restrict__ DL,
                                              const float* __restrict__ DR,
                                              const int* __restrict__ rowptr,
                                              const int* __restrict__ csrc,
                                              float* __restrict__ OUT) {
    const int lane = threadIdx.x & 63;
    const int wid = threadIdx.x >> 6;
    const int n = blockIdx.x * 4 + wid;
    if (n >= NN) return;
    const int beg = rowptr[n];
    const int end = rowptr[n + 1];
    const int e1 = end - 1;
    const int q = lane >> 4;
    const uint jj = lane & 15;

    float4 xr;
    {
        ushort4 u = *(const ushort4*)(XRb + (uint)n * 64u + 4u * jj);
        xr.x = bf2f(u.x); xr.y = bf2f(u.y); xr.z = bf2f(u.z); xr.w = bf2f(u.w);
    }
    float4 at = ((const float4*)att)[jj];
    at.x *= 0.4f; at.y *= 0.4f; at.z *= 0.4f; at.w *= 0.4f;
    const float dRn = DR[n];
    float4 s = {0.f, 0.f, 0.f, 0.f};
    float d = 0.f;

#define GL2(I, U0, U1, D0, D1) {                               \
    uint sa = (uint)csrc[min((I) + q, e1)];                    \
    uint sb = (uint)csrc[min((I) + 4 + q, e1)];                \
    U0 = *(const ushort4*)(XLb + sa * 64u + 4u * jj);          \
    U1 = *(const ushort4*)(XLb + sb * 64u + 4u * jj);          \
    D0 = DL[sa];                                               \
    D1 = DL[sb]; }

#define EDGE2(U, DLV, II) {                                    \
    float v0 = bf2f((U).x), v1 = bf2f((U).y);                  \
    float v2 = bf2f((U).z), v3 = bf2f((U).w);                  \
    float t =      at.x * fabsf(v0 + xr.x);                    \
    t = fmaf(at.y, fabsf(v1 + xr.y), t);                       \
    t = fmaf(at.z, fabsf(v2 + xr.z), t);                       \
    t = fmaf(at.w, fabsf(v3 + xr.w), t);                       \
    float p = expclamp(sum16(t) + (DLV) + dRn);                \
    p = ((II) < end) ? p : 0.f;                                \
    d += p;                                                    \
    s.x = fmaf(p, v0, s.x); s.y = fmaf(p, v1, s.y);            \
    s.z = fmaf(p, v2, s.z); s.w = fmaf(p, v3, s.w); }

    if (beg < end) {
        ushort4 cu0, cu1;
        float cd0, cd1;
        GL2(beg, cu0, cu1, cd0, cd1)
        for (int i = beg; i < end; i += 8) {
            ushort4 nu0, nu1;
            float nd0, nd1;
            GL2(i + 8, nu0, nu1, nd0, nd1)
            EDGE2(cu0, cd0, i + q)
            EDGE2(cu1, cd1, i + 4 + q)
            cu0 = nu0; cu1 = nu1;
            cd0 = nd0; cd1 = nd1;
        }
    }
#undef GL2
#undef EDGE2

    d   += __shfl_xor(d, 16);   d   += __shfl_xor(d, 32);
    s.x += __shfl_xor(s.x, 16); s.x += __shfl_xor(s.x, 32);
    s.y += __shfl_xor(s.y, 16); s.y += __shfl_xor(s.y, 32);
    s.z += __shfl_xor(s.z, 16); s.z += __shfl_xor(s.z, 32);
    s.w += __shfl_xor(s.w, 16); s.w += __shfl_xor(s.w, 32);

    if (lane < 16) {
        float inv = (d > 0.f) ? 1.f / d : 0.f;
        float4 bv = ((const float4*)bias)[jj];
        float4 o;
        o.x = fmaf(s.x, inv, bv.x);
        o.y = fmaf(s.y, inv, bv.y);
        o.z = fmaf(s.z, inv, bv.z);
        o.w = fmaf(s.w, inv, bv.w);
        *(float4*)(OUT + (uint)n * 64u + 4u * jj) = o;
    }
}

// ---------------------------------------------------------------------------
extern "C" void kernel_launch(void* const* d_in, const int* in_sizes, int n_in,
                              void* d_out, int out_size, void* d_ws, size_t ws_size,
                              hipStream_t stream) {
    const float* x    = (const float*)d_in[0];
    const int*   ei   = (const int*)d_in[1];
    const int*   esrc = ei;
    const int*   edst = ei + EE;

    const float* Wl0 = (const float*)d_in[2];
    const float* bl0 = (const float*)d_in[3];
    const float* Wr0 = (const float*)d_in[4];
    const float* br0 = (const float*)d_in[5];
    const float* at0 = (const float*)d_in[6];
    const float* b0  = (const float*)d_in[7];
    const float* rs0 = (const float*)d_in[8];
    const float* Wl1 = (const float*)d_in[9];
    const float* bl1 = (const float*)d_in[10];
    const float* Wr1 = (const float*)d_in[11];
    const float* br1 = (const float*)d_in[12];
    const float* at1 = (const float*)d_in[13];
    const float* b1  = (const float*)d_in[14];
    const float* rs1 = (const float*)d_in[15];
    const float* Wl2 = (const float*)d_in[16];
    const float* bl2 = (const float*)d_in[17];
    const float* Wr2 = (const float*)d_in[18];
    const float* br2 = (const float*)d_in[19];
    const float* at2 = (const float*)d_in[20];
    const float* b2  = (const float*)d_in[21];

    float* out = (float*)d_out;

    // --- workspace layout ---
    ushort* XLb = (ushort*)d_ws;               // [NN*128] bf16 (gather payload)
    ushort* XRb = XLb + (size_t)NN * 128;             // [NN*128] bf16 (XR)
    float* RES = (float*)(XRb + (size_t)NN * 128);    // [NN*128] fp32
    ushort* Xh = (ushort*)(RES + (size_t)NN * 128);   // [NN*128] bf16-hi (H)
    ushort* Xl_ = Xh + (size_t)NN * 128;              // [NN*128] bf16-lo (H)
    float* DLarr = (float*)(Xl_ + (size_t)NN * 128);  // [NN*4] fp32 dotL
    float* DRarr = DLarr + (size_t)NN * 4;            // [NN*4] fp32 dotR
    ushort* Wth = (ushort*)(DRarr + (size_t)NN * 4);
    const int wsz[8] = {16384, 16384, 16384, 16384, 16384, 16384, 8192, 8192};
    ushort* th[8]; ushort* tl[8];
    {
        ushort* p = Wth;
        for (int i = 0; i < 8; ++i) { th[i] = p; p += wsz[i]; }
        for (int i = 0; i < 8; ++i) { tl[i] = p; p += wsz[i]; }
    }
    int* bcnt   = (int*)(Wth + 2 * (6 * 16384 + 2 * 8192));  // 256 (memset)
    int* bbase  = bcnt + 256;                  // 256
    int* bcur   = bbase + 256;                 // 256
    int* rowptr = bcur + 256;                  // NN+1
    int* csrc   = rowptr + (NN + 1);           // EE
    uint* ebuf  = (uint*)(csrc + EE);          // EE

    // --- bucketed CSR build (graph identical across layers) ---
    hipMemsetAsync(bcnt, 0, 256 * sizeof(int), stream);
    const int ebk = (EE + EPB - 1) / EPB;      // 196
    k_bktcnt<<<ebk, 256, 0, stream>>>(edst, bcnt);
    k_bscan<<<1, 256, 0, stream>>>(bcnt, bbase, bcur);
    k_bktplace<<<ebk, 256, 0, stream>>>(esrc, edst, bcur, ebuf);
    k_bktfin<<<NBK, 256, 0, stream>>>(ebuf, bbase, bcnt, rowptr, csrc);

    // --- weight conversion ---
    WPack wp;
    const float* Ws[8] = {Wl0, Wr0, rs0, Wl1, Wr1, rs1, Wl2, Wr2};
    const int fouts[8] = {128, 128, 128, 128, 128, 128, 64, 64};
    for (int i = 0; i < 8; ++i) { wp.W[i] = Ws[i]; wp.Th[i] = th[i]; wp.Tl[i] = tl[i]; wp.fout[i] = fouts[i]; }
    k_conv_w<<<dim3(64, 8), 256, 0, stream>>>(wp);

    const int gemm_gx = (NN + 127) / 128;      // 391 row-tiles (128 rows/block)
    const int agg_grid = (NN + 3) / 4;

    // --- Layer 0 (A from fp32 x; 3 weight mats fused; split-K staging) ---
    k_gemm_fused<128, 3, true, 2><<<dim3(gemm_gx, 4), 512, 0, stream>>>(x, nullptr, nullptr,
        th[0], tl[0], bl0, th[1], tl[1], br0, th[2], tl[2], at0, DLarr, DRarr, XLb, XRb, RES);
    k_agg01<<<agg_grid, 256, 0, stream>>>(XLb, XRb, (const float4*)RES,
        at0, b0, DLarr, DRarr, rowptr, csrc, Xh, Xl_);

    // --- Layer 1 ---
    k_gemm_fused<128, 3, false, 2><<<dim3(gemm_gx, 4), 512, 0, stream>>>(nullptr, Xh, Xl_,
        th[3], tl[3], bl1, th[4], tl[4], br1, th[5], tl[5], at1, DLarr, DRarr, XLb, XRb, RES);
    k_agg01<<<agg_grid, 256, 0, stream>>>(XLb, XRb, (const float4*)RES,
        at1, b1, DLarr, DRarr, rowptr, csrc, Xh, Xl_);

    // --- Layer 2 (heads=1, C=64; dot partials via atomics into zeroed DL/DR) ---
    hipMemsetAsync(DLarr, 0, NN * sizeof(float), stream);
    hipMemsetAsync(DRarr, 0, NN * sizeof(float), stream);
    k_gemm_fused<64, 2, false, 2><<<dim3(gemm_gx, 2), 512, 0, stream>>>(nullptr, Xh, Xl_,
        th[6], tl[6], bl2, th[7], tl[7], br2, nullptr, nullptr, at2, DLarr, DRarr, XLb, XRb, nullptr);
    k_agg2<<<agg_grid, 256, 0, stream>>>(XLb, XRb, at2, b2, DLarr, DRarr, rowptr, csrc, out);
}

// Round 11
// 353.154 us; speedup vs baseline: 1.0733x; 1.0086x over previous
//
#include <hip/hip_runtime.h>
#include <math.h>

// Problem constants (from reference)
#define NN 50000
#define EE 800000
#define NBK 196    // node buckets (256 nodes each): ceil(50000/256)
#define EPB 4096   // edges per pass-A block: ceil(800000/4096) = 196 blocks

// exp2-folded softmax scales: p = exp2(L2E*logit) == exp(logit)
#define SC04 0.57707802f   // 0.4 * log2(e)
#define SC06 0.86561702f   // 0.6 * log2(e)

typedef short v8s __attribute__((ext_vector_type(8)));
typedef float v4f __attribute__((ext_vector_type(4)));

__device__ __forceinline__ ushort f2bf(float f) {
    uint u = __float_as_uint(f);
    uint r = (u + 0x7fffu + ((u >> 16) & 1u)) >> 16;
    return (ushort)r;
}
__device__ __forceinline__ float bf2f(ushort h) {
    return __uint_as_float(((uint)h) << 16);
}

// async global->LDS, 16B per lane (dest = wave-uniform base + lane*16)
__device__ __forceinline__ void gld_lds16(const void* g, void* l) {
    __builtin_amdgcn_global_load_lds(
        (const __attribute__((address_space(1))) void*)g,
        (__attribute__((address_space(3))) void*)l, 16, 0, 0);
}

// DPP partial reductions (no LDS pipe).
template <int CTRL>
__device__ __forceinline__ float dppadd(float x) {
    int y = __builtin_amdgcn_update_dpp(0, __float_as_int(x), CTRL, 0xf, 0xf, true);
    return x + __int_as_float(y);
}
__device__ __forceinline__ float sum8(float x) {   // sum within aligned 8-groups
    x = dppadd<0xB1>(x);    // quad_perm xor1
    x = dppadd<0x4E>(x);    // quad_perm xor2
    x = dppadd<0x141>(x);   // row_half_mirror
    return x;
}
__device__ __forceinline__ float sum16(float x) {  // sum within aligned 16-rows
    x = sum8(x);
    x = dppadd<0x140>(x);   // row_mirror
    return x;
}
// native 2^x with overflow guard (underflow -> 0 is fine)
__device__ __forceinline__ float exp2c(float t) {
    return __builtin_amdgcn_exp2f(fminf(t, 126.f));
}

// ---------------------------------------------------------------------------
// Bucketed CSR build — no per-node global atomics, no random global writes.
// ---------------------------------------------------------------------------
__global__ __launch_bounds__(256) void k_bktcnt(const int* __restrict__ edst,
                                                int* __restrict__ bcnt) {
    __shared__ int h[NBK];
    int t = threadIdx.x;
    if (t < NBK) h[t] = 0;
    __syncthreads();
    int eb = blockIdx.x * EPB;
    #pragma unroll
    for (int k = 0; k < EPB / 256; ++k) {
        int e = eb + k * 256 + t;
        if (e < EE) atomicAdd(&h[edst[e] >> 8], 1);
    }
    __syncthreads();
    if (t < NBK && h[t]) atomicAdd(&bcnt[t], h[t]);
}

__global__ __launch_bounds__(256) void k_bscan(const int* __restrict__ bcnt,
                                               int* __restrict__ bbase,
                                               int* __restrict__ bcur) {
    __shared__ int sm[256];
    int t = threadIdx.x;
    int v = (t < NBK) ? bcnt[t] : 0;
    sm[t] = v;
    __syncthreads();
    for (int o = 1; o < 256; o <<= 1) {
        int a = (t >= o) ? sm[t - o] : 0;
        __syncthreads();
        sm[t] += a;
        __syncthreads();
    }
    if (t < NBK) { int ex = sm[t] - v; bbase[t] = ex; bcur[t] = ex; }
}

__global__ __launch_bounds__(256) void k_bktplace(const int* __restrict__ esrc,
                                                  const int* __restrict__ edst,
                                                  int* __restrict__ bcur,
                                                  uint* __restrict__ ebuf) {
    __shared__ int h[NBK];
    __shared__ int base[NBK];
    int t = threadIdx.x;
    if (t < NBK) h[t] = 0;
    __syncthreads();
    int eb = blockIdx.x * EPB;
    int pk[EPB / 256];   // (bucket<<16)|local_rank per edge
    #pragma unroll
    for (int k = 0; k < EPB / 256; ++k) {
        int e = eb + k * 256 + t;
        pk[k] = -1;
        if (e < EE) {
            int b = edst[e] >> 8;
            int r = atomicAdd(&h[b], 1);
            pk[k] = (b << 16) | r;
        }
    }
    __syncthreads();
    if (t < NBK && h[t]) base[t] = atomicAdd(&bcur[t], h[t]);
    __syncthreads();
    #pragma unroll
    for (int k = 0; k < EPB / 256; ++k) {
        int e = eb + k * 256 + t;
        if (e < EE) {
            int b = pk[k] >> 16;
            int r = pk[k] & 0xFFFF;
            uint dl = (uint)(edst[e] & 255);
            ebuf[base[b] + r] = (dl << 16) | (uint)esrc[e];
        }
    }
}

// one block per bucket: per-node degree + scan + cursor all in LDS.
__global__ __launch_bounds__(256) void k_bktfin(const uint* __restrict__ ebuf,
                                                const int* __restrict__ bbase,
                                                const int* __restrict__ bcnt,
                                                int* __restrict__ rowptr,
                                                int* __restrict__ csrc) {
    __shared__ int deg[256];
    __shared__ int sm[256];
    __shared__ int cur[256];
    const int b = blockIdx.x;
    const int t = threadIdx.x;
    const int eb = bbase[b];
    const int ec = bcnt[b];
    deg[t] = 0;
    __syncthreads();
    for (int k = t; k < ec; k += 256)
        atomicAdd(&deg[ebuf[eb + k] >> 16], 1);
    __syncthreads();
    int v = deg[t];
    sm[t] = v;
    __syncthreads();
    for (int o = 1; o < 256; o <<= 1) {
        int a = (t >= o) ? sm[t - o] : 0;
        __syncthreads();
        sm[t] += a;
        __syncthreads();
    }
    int node = b * 256 + t;
    if (node < NN) rowptr[node + 1] = eb + sm[t];
    if (node == 0) rowptr[0] = 0;
    cur[t] = sm[t] - v;   // exclusive
    __syncthreads();
    for (int k = t; k < ec; k += 256) {
        uint u = ebuf[eb + k];
        int nl = (int)(u >> 16);
        int r = atomicAdd(&cur[nl], 1);
        csrc[eb + r] = (int)(u & 0xFFFFu);
    }
}

// ---------------------------------------------------------------------------
// Weight conversion: W [128 x FOUT] fp32 -> bf16 hi/lo in MFMA-fragment order.
// ---------------------------------------------------------------------------
struct WPack {
    const float* W[8];
    ushort* Th[8];
    ushort* Tl[8];
    int fout[8];
};

__global__ __launch_bounds__(256) void k_conv_w(WPack p) {
    int wi = blockIdx.y;
    int fout = p.fout[wi];
    int total = 128 * fout;
    int i = blockIdx.x * 256 + threadIdx.x;
    if (i >= total) return;
    int k = i / fout;
    int n = i - k * fout;
    float f = p.W[wi][i];
    ushort h = f2bf(f);
    float lo = f - bf2f(h);
    int t = n >> 4, m = n & 15, c = k >> 5, quad = (k >> 3) & 3, j = k & 7;
    int flat = ((((t * 4 + c) * 4 + quad) * 16 + m) << 3) + j;
    p.Th[wi][flat] = h;
    p.Tl[wi][flat] = f2bf(lo);
}

// ---------------------------------------------------------------------------
// Fused split-bf16 MFMA GEMM + attention-dot epilogue, split-K staging
// (round-10 structure, 24KB/16KB LDS). DL/DR stored pre-scaled by
// 0.6*log2(e) for the exp2-folded softmax.
// ---------------------------------------------------------------------------
template <int FOUT, int NMAT, bool CVT, int TS>
__global__ __launch_bounds__(512) void k_gemm_fused(
    const float* __restrict__ Xf,
    const ushort* __restrict__ Xh, const ushort* __restrict__ Xl,
    const ushort* __restrict__ T0h, const ushort* __restrict__ T0l, const float* __restrict__ B0,
    const ushort* __restrict__ T1h, const ushort* __restrict__ T1l, const float* __restrict__ B1,
    const ushort* __restrict__ T2h, const ushort* __restrict__ T2l,
    const float* __restrict__ ATT, float* __restrict__ DL, float* __restrict__ DR,
    ushort* __restrict__ O0b, ushort* __restrict__ O1b, float* __restrict__ O2)
{
    static_assert(TS == 2, "split-K staging assumes TS==2");
    __shared__ __align__(16) ushort Bs[NMAT * 4096];

    const int tid  = threadIdx.x;
    const int lane = tid & 63;
    const int wid  = tid >> 6;                    // 0..7
    const int m    = lane & 15;
    const int quad = lane >> 4;
    const int row0 = blockIdx.x * 128 + wid * 16;
    const int t0   = blockIdx.y * TS;

    const ushort* tb0 = T0h; const ushort* tb1 = T0l;
    const ushort* tb2 = T1h; const ushort* tb3 = T1l;
    const ushort* tb4 = T2h; const ushort* tb5 = T2l;

    auto stageHalf = [&](int h) {
        const int cidx = (tid & 255) * 8;      // ushort offset in 2048-region
        const int tt   = cidx >> 10;
        const int rem  = cidx & 1023;
        const size_t srcoff = (size_t)(t0 + tt) * 2048 + h * 1024 + rem;
        {
            const ushort* tp = (tid < 256) ? tb0 : tb1;
            gld_lds16(tp + srcoff, &Bs[0 * 4096 + tid * 8]);
        }
        {
            const ushort* tp = (tid < 256) ? tb2 : tb3;
            gld_lds16(tp + srcoff, &Bs[1 * 4096 + tid * 8]);
        }
        if constexpr (NMAT == 3) {
            const ushort* tp = (tid < 256) ? tb4 : tb5;
            gld_lds16(tp + srcoff, &Bs[2 * 4096 + tid * 8]);
        }
    };

    // ---- A fragments (per-wave rows), loaded once ----
    v8s ah[4], al[4];
    {
        int arow = row0 + m;
        if (arow > NN - 1) arow = NN - 1;
        #pragma unroll
        for (int c = 0; c < 4; ++c) {
            size_t off = (size_t)arow * 128 + c * 32 + quad * 8;
            if constexpr (CVT) {
                float4 f0 = *(const float4*)(Xf + off);
                float4 f1 = *(const float4*)(Xf + off + 4);
                const float fe[8] = {f0.x, f0.y, f0.z, f0.w, f1.x, f1.y, f1.z, f1.w};
                #pragma unroll
                for (int e = 0; e < 8; ++e) {
                    ushort hh = f2bf(fe[e]);
                    float lo = fe[e] - bf2f(hh);
                    ah[c][e] = (short)hh;
                    al[c][e] = (short)(__float_as_uint(lo) >> 16);  // truncate lo
                }
            } else {
                ah[c] = *(const v8s*)(Xh + off);
                al[c] = *(const v8s*)(Xl + off);
            }
        }
    }

    v4f a0[TS], a1[TS], a2[TS];
    #pragma unroll
    for (int tt = 0; tt < TS; ++tt) {
        a0[tt] = v4f{0.f, 0.f, 0.f, 0.f};
        a1[tt] = v4f{0.f, 0.f, 0.f, 0.f};
        a2[tt] = v4f{0.f, 0.f, 0.f, 0.f};
    }

    stageHalf(0);
    __syncthreads();   // staging of half 0 visible

    #pragma unroll
    for (int h = 0; h < 2; ++h) {
        if (h == 1) {
            __syncthreads();   // all ds_reads of half 0 done
            stageHalf(1);
            __syncthreads();   // staging of half 1 visible
        }
        #pragma unroll
        for (int tt = 0; tt < TS; ++tt) {
            #pragma unroll
            for (int lc = 0; lc < 2; ++lc) {
                const int c = 2 * h + lc;      // global K-quarter
                const int fo = tt * 1024 + (lc * 4 + quad) * 128 + m * 8;
                v8s b0h = *(const v8s*)&Bs[0 * 2048 + fo];
                v8s b0l = *(const v8s*)&Bs[1 * 2048 + fo];
                v8s b1h = *(const v8s*)&Bs[2 * 2048 + fo];
                v8s b1l = *(const v8s*)&Bs[3 * 2048 + fo];
                a0[tt] = __builtin_amdgcn_mfma_f32_16x16x32_bf16(al[c], b0h, a0[tt], 0, 0, 0);
                a1[tt] = __builtin_amdgcn_mfma_f32_16x16x32_bf16(al[c], b1h, a1[tt], 0, 0, 0);
                a0[tt] = __builtin_amdgcn_mfma_f32_16x16x32_bf16(ah[c], b0l, a0[tt], 0, 0, 0);
                a1[tt] = __builtin_amdgcn_mfma_f32_16x16x32_bf16(ah[c], b1l, a1[tt], 0, 0, 0);
                a0[tt] = __builtin_amdgcn_mfma_f32_16x16x32_bf16(ah[c], b0h, a0[tt], 0, 0, 0);
                a1[tt] = __builtin_amdgcn_mfma_f32_16x16x32_bf16(ah[c], b1h, a1[tt], 0, 0, 0);
                if constexpr (NMAT == 3) {
                    v8s b2h = *(const v8s*)&Bs[4 * 2048 + fo];
                    v8s b2l = *(const v8s*)&Bs[5 * 2048 + fo];
                    a2[tt] = __builtin_amdgcn_mfma_f32_16x16x32_bf16(al[c], b2h, a2[tt], 0, 0, 0);
                    a2[tt] = __builtin_amdgcn_mfma_f32_16x16x32_bf16(ah[c], b2l, a2[tt], 0, 0, 0);
                    a2[tt] = __builtin_amdgcn_mfma_f32_16x16x32_bf16(ah[c], b2h, a2[tt], 0, 0, 0);
                }
            }
        }
    }

    // ---- epilogue: bias, dot partials (pre-scaled by 0.6*log2e), stores ----
    float dp0[4] = {0.f, 0.f, 0.f, 0.f};
    float dp1[4] = {0.f, 0.f, 0.f, 0.f};
    #pragma unroll
    for (int tt = 0; tt < TS; ++tt) {
        const int t = t0 + tt;
        const int col = t * 16 + m;
        const float bad0 = B0[col];
        const float bad1 = B1[col];
        const float attc = ATT[col];
        #pragma unroll
        for (int j = 0; j < 4; ++j) {
            float o0v = a0[tt][j] + bad0;
            float o1v = a1[tt][j] + bad1;
            dp0[j] = fmaf(attc, o0v, dp0[j]);
            dp1[j] = fmaf(attc, o1v, dp1[j]);
            int r = row0 + quad * 4 + j;
            if (r < NN) {
                O0b[(size_t)r * FOUT + col] = f2bf(o0v);
                O1b[(size_t)r * FOUT + col] = f2bf(o1v);
                if constexpr (NMAT == 3) O2[(size_t)r * FOUT + col] = a2[tt][j];
            }
        }
        if constexpr (FOUT == 128) {
            if ((t & 1) == 1) {   // head hd = t>>1 complete -> reduce + store
                const int hd = t >> 1;
                #pragma unroll
                for (int j = 0; j < 4; ++j) {
                    float s0 = sum16(dp0[j]);
                    float s1 = sum16(dp1[j]);
                    int r = row0 + quad * 4 + j;
                    if (m == 0 && r < NN) {
                        DL[(size_t)r * 4 + hd] = SC06 * s0;
                        DR[(size_t)r * 4 + hd] = SC06 * s1;
                    }
                    dp0[j] = 0.f;
                    dp1[j] = 0.f;
                }
            }
        }
    }
    if constexpr (FOUT == 64) {   // head spans all 4 t -> partial, atomic
        #pragma unroll
        for (int j = 0; j < 4; ++j) {
            float s0 = sum16(dp0[j]);
            float s1 = sum16(dp1[j]);
            int r = row0 + quad * 4 + j;
            if (m == 0 && r < NN) {
                atomicAdd(&DL[r], SC06 * s0);
                atomicAdd(&DR[r], SC06 * s1);
            }
        }
    }
}

// ---------------------------------------------------------------------------
// Aggregation layers 0/1 — 32 lanes/edge, 4 channels/lane, 2-stage pipeline.
// Full 8-edge packets processed UNMASKED; one masked tail packet. exp2-folded
// softmax: at pre-scaled by 0.4*log2e, DL/DR pre-scaled by 0.6*log2e ->
// p = v_exp(sum8(t)+DL+DR) directly.
// ---------------------------------------------------------------------------
__global__ __launch_bounds__(256) void k_agg01(const ushort* __restrict__ XLb,
                                               const ushort* __restrict__ XRb,
                                               const float4* __restrict__ RES4,
                                               const float* __restrict__ att,
                                               const float* __restrict__ bias,
                                               const float* __restrict__ DL,
                                               const float* __restrict__ DR,
                                               const int* __restrict__ rowptr,
                                               const int* __restrict__ csrc,
                                               ushort* __restrict__ Hh,
                                               ushort* __restrict__ Hl) {
    const int lane = threadIdx.x & 63;
    const int wid = threadIdx.x >> 6;
    const int n = blockIdx.x * 4 + wid;
    if (n >= NN) return;
    const int beg = rowptr[n];
    const int end = rowptr[n + 1];
    const int e1 = end - 1;
    const int half = lane >> 5;
    const uint j = lane & 31;
    const uint head = j >> 3;

    float4 xr;
    {
        ushort4 u = *(const ushort4*)(XRb + (uint)n * 128u + 4u * j);
        xr.x = bf2f(u.x); xr.y = bf2f(u.y); xr.z = bf2f(u.z); xr.w = bf2f(u.w);
    }
    float4 at = ((const float4*)att)[j];
    at.x *= SC04; at.y *= SC04; at.z *= SC04; at.w *= SC04;
    const float dRn = DR[(uint)n * 4u + head];
    float4 s = {0.f, 0.f, 0.f, 0.f};
    float d = 0.f;

#define GL01(I, U0, U1, U2, U3, D0, D1, D2, D3) {              \
    uint sa = (uint)csrc[min((I) + half, e1)];                 \
    uint sb = (uint)csrc[min((I) + 2 + half, e1)];             \
    uint sc = (uint)csrc[min((I) + 4 + half, e1)];             \
    uint sd = (uint)csrc[min((I) + 6 + half, e1)];             \
    U0 = *(const ushort4*)(XLb + sa * 128u + 4u * j);          \
    U1 = *(const ushort4*)(XLb + sb * 128u + 4u * j);          \
    U2 = *(const ushort4*)(XLb + sc * 128u + 4u * j);          \
    U3 = *(const ushort4*)(XLb + sd * 128u + 4u * j);          \
    D0 = DL[sa * 4u + head];                                   \
    D1 = DL[sb * 4u + head];                                   \
    D2 = DL[sc * 4u + head];                                   \
    D3 = DL[sd * 4u + head]; }

#define EDGEBODY(U, DLV)                                       \
    float v0 = bf2f((U).x), v1 = bf2f((U).y);                  \
    float v2 = bf2f((U).z), v3 = bf2f((U).w);                  \
    float t =      at.x * fabsf(v0 + xr.x);                    \
    t = fmaf(at.y, fabsf(v1 + xr.y), t);                       \
    t = fmaf(at.z, fabsf(v2 + xr.z), t);                       \
    t = fmaf(at.w, fabsf(v3 + xr.w), t);                       \
    float p = exp2c(sum8(t) + (DLV) + dRn);

#define EDGE01U(U, DLV) {                                      \
    EDGEBODY(U, DLV)                                           \
    d += p;                                                    \
    s.x = fmaf(p, v0, s.x); s.y = fmaf(p, v1, s.y);            \
    s.z = fmaf(p, v2, s.z); s.w = fmaf(p, v3, s.w); }

#define EDGE01M(U, DLV, II) {                                  \
    EDGEBODY(U, DLV)                                           \
    p = ((II) < end) ? p : 0.f;                                \
    d += p;                                                    \
    s.x = fmaf(p, v0, s.x); s.y = fmaf(p, v1, s.y);            \
    s.z = fmaf(p, v2, s.z); s.w = fmaf(p, v3, s.w); }

    if (beg < end) {
        ushort4 cu0, cu1, cu2, cu3;
        float cd0, cd1, cd2, cd3;
        int i = beg;
        GL01(i, cu0, cu1, cu2, cu3, cd0, cd1, cd2, cd3)
        for (; i + 8 <= end; i += 8) {
            ushort4 nu0, nu1, nu2, nu3;
            float nd0, nd1, nd2, nd3;
            GL01(i + 8, nu0, nu1, nu2, nu3, nd0, nd1, nd2, nd3)
            EDGE01U(cu0, cd0)
            EDGE01U(cu1, cd1)
            EDGE01U(cu2, cd2)
            EDGE01U(cu3, cd3)
            cu0 = nu0; cu1 = nu1; cu2 = nu2; cu3 = nu3;
            cd0 = nd0; cd1 = nd1; cd2 = nd2; cd3 = nd3;
        }
        if (i < end) {
            EDGE01M(cu0, cd0, i + half)
            EDGE01M(cu1, cd1, i + 2 + half)
            EDGE01M(cu2, cd2, i + 4 + half)
            EDGE01M(cu3, cd3, i + 6 + half)
        }
    }
#undef GL01
#undef EDGEBODY
#undef EDGE01U
#undef EDGE01M

    d   += __shfl_xor(d, 32);
    s.x += __shfl_xor(s.x, 32);
    s.y += __shfl_xor(s.y, 32);
    s.z += __shfl_xor(s.z, 32);
    s.w += __shfl_xor(s.w, 32);

    if (half == 0) {
        float inv = (d > 0.f) ? 1.f / d : 0.f;
        float4 rv = RES4[(uint)n * 32u + j];
        float4 bv = ((const float4*)bias)[j];
        float o0 = fmaf(s.x, inv, rv.x + bv.x);
        float o1 = fmaf(s.y, inv, rv.y + bv.y);
        float o2 = fmaf(s.z, inv, rv.z + bv.z);
        float o3 = fmaf(s.w, inv, rv.w + bv.w);
        o0 = o0 > 0.f ? o0 : __expf(o0) - 1.f;   // ELU
        o1 = o1 > 0.f ? o1 : __expf(o1) - 1.f;
        o2 = o2 > 0.f ? o2 : __expf(o2) - 1.f;
        o3 = o3 > 0.f ? o3 : __expf(o3) - 1.f;
        ushort4 h, l;
        h.x = f2bf(o0); l.x = f2bf(o0 - bf2f(h.x));
        h.y = f2bf(o1); l.y = f2bf(o1 - bf2f(h.y));
        h.z = f2bf(o2); l.z = f2bf(o2 - bf2f(h.z));
        h.w = f2bf(o3); l.w = f2bf(o3 - bf2f(h.w));
        *(ushort4*)(Hh + (uint)n * 128u + 4u * j) = h;
        *(ushort4*)(Hl + (uint)n * 128u + 4u * j) = l;
    }
}

// ---------------------------------------------------------------------------
// Aggregation layer 2 — F=64, H=1, 16 lanes/edge, 4 channels/lane,
// 2-stage pipeline, full packets unmasked + masked tail. exp2-folded.
// ---------------------------------------------------------------------------
__global__ __launch_bounds__(256) void k_agg2(const ushort* __restrict__ XLb,
                                              const ushort* __restrict__ XRb,
                                              const float* __restrict__ att,
                                              const float* __restrict__ bias,
                                              const float* __restrict__ DL,
                                              const float* __restrict__ DR,
                                              const int* __restrict__ rowptr,
                                              const int* __restrict__ csrc,
                                              float* __restrict__ OUT) {
    const int lane = threadIdx.x & 63;
    const int wid = threadIdx.x >> 6;
    const int n = blockIdx.x * 4 + wid;
    if (n >= NN) return;
    const int beg = rowptr[n];
    const int end = rowptr[n + 1];
    const int e1 = end - 1;
    const int q = lane >> 4;
    const uint jj = lane & 15;

    float4 xr;
    {
        ushort4 u = *(const ushort4*)(XRb + (uint)n * 64u + 4u * jj);
        xr.x = bf2f(u.x); xr.y = bf2f(u.y); xr.z = bf2f(u.z); xr.w = bf2f(u.w);
    }
    float4 at = ((const float4*)att)[jj];
    at.x *= SC04; at.y *= SC04; at.z *= SC04; at.w *= SC04;
    const float dRn = DR[n];
    float4 s = {0.f, 0.f, 0.f, 0.f};
    float d = 0.f;

#define GL2(I, U0, U1, D0, D1) {                               \
    uint sa = (uint)csrc[min((I) + q, e1)];                    \
    uint sb = (uint)csrc[min((I) + 4 + q, e1)];                \
    U0 = *(const ushort4*)(XLb + sa * 64u + 4u * jj);          \
    U1 = *(const ushort4*)(XLb + sb * 64u + 4u * jj);          \
    D0 = DL[sa];                                               \
    D1 = DL[sb]; }

#define EDGEBODY2(U, DLV)                                      \
    float v0 = bf2f((U).x), v1 = bf2f((U).y);                  \
    float v2 = bf2f((U).z), v3 = bf2f((U).w);                  \
    float t =      at.x * fabsf(v0 + xr.x);                    \
    t = fmaf(at.y, fabsf(v1 + xr.y), t);                       \
    t = fmaf(at.z, fabsf(v2 + xr.z), t);                       \
    t = fmaf(at.w, fabsf(v3 + xr.w), t);                       \
    float p = exp2c(sum16(t) + (DLV) + dRn);

#define EDGE2U(U, DLV) {                                       \
    EDGEBODY2(U, DLV)                                          \
    d += p;                                                    \
    s.x = fmaf(p, v0, s.x); s.y = fmaf(p, v1, s.y);            \
    s.z = fmaf(p, v2, s.z); s.w = fmaf(p, v3, s.w); }

#define EDGE2M(U, DLV, II) {                                   \
    EDGEBODY2(U, DLV)                                          \
    p = ((II) < end) ? p : 0.f;                                \
    d += p;                                                    \
    s.x = fmaf(p, v0, s.x); s.y = fmaf(p, v1, s.y);            \
    s.z = fmaf(p, v2, s.z); s.w = fmaf(p, v3, s.w); }

    if (beg < end) {
        ushort4 cu0, cu1;
        float cd0, cd1;
        int i = beg;
        GL2(i, cu0, cu1, cd0, cd1)
        for (; i + 8 <= end; i += 8) {
            ushort4 nu0, nu1;
            float nd0, nd1;
            GL2(i + 8, nu0, nu1, nd0, nd1)
            EDGE2U(cu0, cd0)
            EDGE2U(cu1, cd1)
            cu0 = nu0; cu1 = nu1;
            cd0 = nd0; cd1 = nd1;
        }
        if (i < end) {
            EDGE2M(cu0, cd0, i + q)
            EDGE2M(cu1, cd1, i + 4 + q)
        }
    }
#undef GL2
#undef EDGEBODY2
#undef EDGE2U
#undef EDGE2M

    d   += __shfl_xor(d, 16);   d   += __shfl_xor(d, 32);
    s.x += __shfl_xor(s.x, 16); s.x += __shfl_xor(s.x, 32);
    s.y += __shfl_xor(s.y, 16); s.y += __shfl_xor(s.y, 32);
    s.z += __shfl_xor(s.z, 16); s.z += __shfl_xor(s.z, 32);
    s.w += __shfl_xor(s.w, 16); s.w += __shfl_xor(s.w, 32);

    if (lane < 16) {
        float inv = (d > 0.f) ? 1.f / d : 0.f;
        float4 bv = ((const float4*)bias)[jj];
        float4 o;
        o.x = fmaf(s.x, inv, bv.x);
        o.y = fmaf(s.y, inv, bv.y);
        o.z = fmaf(s.z, inv, bv.z);
        o.w = fmaf(s.w, inv, bv.w);
        *(float4*)(OUT + (uint)n * 64u + 4u * jj) = o;
    }
}

// ---------------------------------------------------------------------------
extern "C" void kernel_launch(void* const* d_in, const int* in_sizes, int n_in,
                              void* d_out, int out_size, void* d_ws, size_t ws_size,
                              hipStream_t stream) {
    const float* x    = (const float*)d_in[0];
    const int*   ei   = (const int*)d_in[1];
    const int*   esrc = ei;
    const int*   edst = ei + EE;

    const float* Wl0 = (const float*)d_in[2];
    const float* bl0 = (const float*)d_in[3];
    const float* Wr0 = (const float*)d_in[4];
    const float* br0 = (const float*)d_in[5];
    const float* at0 = (const float*)d_in[6];
    const float* b0  = (const float*)d_in[7];
    const float* rs0 = (const float*)d_in[8];
    const float* Wl1 = (const float*)d_in[9];
    const float* bl1 = (const float*)d_in[10];
    const float* Wr1 = (const float*)d_in[11];
    const float* br1 = (const float*)d_in[12];
    const float* at1 = (const float*)d_in[13];
    const float* b1  = (const float*)d_in[14];
    const float* rs1 = (const float*)d_in[15];
    const float* Wl2 = (const float*)d_in[16];
    const float* bl2 = (const float*)d_in[17];
    const float* Wr2 = (const float*)d_in[18];
    const float* br2 = (const float*)d_in[19];
    const float* at2 = (const float*)d_in[20];
    const float* b2  = (const float*)d_in[21];

    float* out = (float*)d_out;

    // --- workspace layout ---
    ushort* XLb = (ushort*)d_ws;               // [NN*128] bf16 (gather payload)
    ushort* XRb = XLb + (size_t)NN * 128;             // [NN*128] bf16 (XR)
    float* RES = (float*)(XRb + (size_t)NN * 128);    // [NN*128] fp32
    ushort* Xh = (ushort*)(RES + (size_t)NN * 128);   // [NN*128] bf16-hi (H)
    ushort* Xl_ = Xh + (size_t)NN * 128;              // [NN*128] bf16-lo (H)
    float* DLarr = (float*)(Xl_ + (size_t)NN * 128);  // [NN*4] fp32 dotL
    float* DRarr = DLarr + (size_t)NN * 4;            // [NN*4] fp32 dotR
    ushort* Wth = (ushort*)(DRarr + (size_t)NN * 4);
    const int wsz[8] = {16384, 16384, 16384, 16384, 16384, 16384, 8192, 8192};
    ushort* th[8]; ushort* tl[8];
    {
        ushort* p = Wth;
        for (int i = 0; i < 8; ++i) { th[i] = p; p += wsz[i]; }
        for (int i = 0; i < 8; ++i) { tl[i] = p; p += wsz[i]; }
    }
    int* bcnt   = (int*)(Wth + 2 * (6 * 16384 + 2 * 8192));  // 256 (memset)
    int* bbase  = bcnt + 256;                  // 256
    int* bcur   = bbase + 256;                 // 256
    int* rowptr = bcur + 256;                  // NN+1
    int* csrc   = rowptr + (NN + 1);           // EE
    uint* ebuf  = (uint*)(csrc + EE);          // EE

    // --- bucketed CSR build (graph identical across layers) ---
    hipMemsetAsync(bcnt, 0, 256 * sizeof(int), stream);
    const int ebk = (EE + EPB - 1) / EPB;      // 196
    k_bktcnt<<<ebk, 256, 0, stream>>>(edst, bcnt);
    k_bscan<<<1, 256, 0, stream>>>(bcnt, bbase, bcur);
    k_bktplace<<<ebk, 256, 0, stream>>>(esrc, edst, bcur, ebuf);
    k_bktfin<<<NBK, 256, 0, stream>>>(ebuf, bbase, bcnt, rowptr, csrc);

    // --- weight conversion ---
    WPack wp;
    const float* Ws[8] = {Wl0, Wr0, rs0, Wl1, Wr1, rs1, Wl2, Wr2};
    const int fouts[8] = {128, 128, 128, 128, 128, 128, 64, 64};
    for (int i = 0; i < 8; ++i) { wp.W[i] = Ws[i]; wp.Th[i] = th[i]; wp.Tl[i] = tl[i]; wp.fout[i] = fouts[i]; }
    k_conv_w<<<dim3(64, 8), 256, 0, stream>>>(wp);

    const int gemm_gx = (NN + 127) / 128;      // 391 row-tiles (128 rows/block)
    const int agg_grid = (NN + 3) / 4;

    // --- Layer 0 (A from fp32 x; 3 weight mats fused; split-K staging) ---
    k_gemm_fused<128, 3, true, 2><<<dim3(gemm_gx, 4), 512, 0, stream>>>(x, nullptr, nullptr,
        th[0], tl[0], bl0, th[1], tl[1], br0, th[2], tl[2], at0, DLarr, DRarr, XLb, XRb, RES);
    k_agg01<<<agg_grid, 256, 0, stream>>>(XLb, XRb, (const float4*)RES,
        at0, b0, DLarr, DRarr, rowptr, csrc, Xh, Xl_);

    // --- Layer 1 ---
    k_gemm_fused<128, 3, false, 2><<<dim3(gemm_gx, 4), 512, 0, stream>>>(nullptr, Xh, Xl_,
        th[3], tl[3], bl1, th[4], tl[4], br1, th[5], tl[5], at1, DLarr, DRarr, XLb, XRb, RES);
    k_agg01<<<agg_grid, 256, 0, stream>>>(XLb, XRb, (const float4*)RES,
        at1, b1, DLarr, DRarr, rowptr, csrc, Xh, Xl_);

    // --- Layer 2 (heads=1, C=64; dot partials via atomics into zeroed DL/DR) ---
    hipMemsetAsync(DLarr, 0, NN * sizeof(float), stream);
    hipMemsetAsync(DRarr, 0, NN * sizeof(float), stream);
    k_gemm_fused<64, 2, false, 2><<<dim3(gemm_gx, 2), 512, 0, stream>>>(nullptr, Xh, Xl_,
        th[6], tl[6], bl2, th[7], tl[7], br2, nullptr, nullptr, at2, DLarr, DRarr, XLb, XRb, nullptr);
    k_agg2<<<agg_grid, 256, 0, stream>>>(XLb, XRb, at2, b2, DLarr, DRarr, rowptr, csrc, out);
}